// Round 2
// baseline (242.015 us; speedup 1.0000x reference)
//
#include <hip/hip_runtime.h>
#include <hip/hip_bf16.h>

// Problem shapes (fixed):
//   hidden_states fp32 [WORLD=8][SEQ=2048][HID=4096]
//   gate_proj     fp32 [OUTD=8192][HID=4096]
//   out           fp32 [SEQ=2048][OUTD=8192]
// out = (sum_w hs[w]) @ W^T   (reduce-scatter sum commutes into the GEMM)

#define HID   4096
#define SEQ   2048
#define WORLD 8
#define OUTD  8192

typedef __bf16 bf16x8 __attribute__((ext_vector_type(8)));
typedef short  s16x8  __attribute__((ext_vector_type(8)));
typedef float  f32x4  __attribute__((ext_vector_type(4)));

typedef const __attribute__((address_space(1))) void* gas1_ptr;
typedef __attribute__((address_space(3))) void*       las3_ptr;

static __device__ __forceinline__ unsigned short f2bf(float f) {
    union { float f; unsigned u; } v; v.f = f;
    unsigned u = v.u;
    u += 0x7fffu + ((u >> 16) & 1u);   // round-to-nearest-even
    return (unsigned short)(u >> 16);
}

// ---------------- Kernel 1: reduce over world dim + cast to bf16 ----------------
__global__ void reduce_x_kernel(const float* __restrict__ hs,
                                unsigned short* __restrict__ xb) {
    const int total4 = SEQ * HID / 4;
    const float4* h4 = (const float4*)hs;
    ushort4* o4 = (ushort4*)xb;
    for (int i = blockIdx.x * blockDim.x + threadIdx.x; i < total4;
         i += gridDim.x * blockDim.x) {
        float4 s = h4[i];
        #pragma unroll
        for (int w = 1; w < WORLD; ++w) {
            float4 t = h4[i + w * total4];
            s.x += t.x; s.y += t.y; s.z += t.z; s.w += t.w;
        }
        ushort4 o;
        o.x = f2bf(s.x); o.y = f2bf(s.y); o.z = f2bf(s.z); o.w = f2bf(s.w);
        o4[i] = o;
    }
}

// ---------------- Kernel 2: cast W to bf16 ----------------
__global__ void convert_w_kernel(const float* __restrict__ w,
                                 unsigned short* __restrict__ wb) {
    const int total4 = OUTD * HID / 4;
    const float4* w4 = (const float4*)w;
    ushort4* o4 = (ushort4*)wb;
    for (int i = blockIdx.x * blockDim.x + threadIdx.x; i < total4;
         i += gridDim.x * blockDim.x) {
        float4 s = w4[i];
        ushort4 o;
        o.x = f2bf(s.x); o.y = f2bf(s.y); o.z = f2bf(s.z); o.w = f2bf(s.w);
        o4[i] = o;
    }
}

// ---------------- Kernel 3: 256x256 8-phase bf16 GEMM  C = A * B^T ----------------
// M=SEQ=2048, N=OUTD=8192, K=HID=4096. 8 waves (2Mx4N), 128x64 out per wave.
// LDS: double-buffered A[2][256][64], B[2][256][64] bf16 = 128 KiB.
// Swizzle: 16B slot' = slot ^ (row&7); applied on the pre-swizzled GLOBAL source
// (global_load_lds writes linearly) and on the ds_read address (rule #21).
// Per K-tile: 4 phases (C-quadrants, 16 MFMA each); ds_reads done by phase 3 so
// buffers are writable at phase 4. Counted vmcnt(4) once per K-tile, never 0
// until the 2-tile tail. Raw s_barrier (no compiler vmcnt drain). setprio on MFMA.

#define BM 256
#define BN 256
#define BK 64
#define KSTEPS (HID / BK)   // 64

__global__ __launch_bounds__(512, 2)
void gemm_bt_kernel(const unsigned short* __restrict__ A,
                    const unsigned short* __restrict__ B,
                    float* __restrict__ C) {
    __shared__ __align__(16) unsigned short lsA[2][BM * BK];   // 64 KiB
    __shared__ __align__(16) unsigned short lsB[2][BN * BK];   // 64 KiB

    const int tid  = threadIdx.x;
    const int lane = tid & 63;
    const int wave = tid >> 6;
    const int wm   = wave >> 2;     // 0..1  -> rows wm*128
    const int wn   = wave & 3;      // 0..3  -> cols wn*64

    // XCD-aware swizzle: grid=256 (=32 per XCD). XCD x owns row-panel bm=x
    // (A panel 2 MB -> L2-resident per XCD; B streams via L3).
    const int bid    = blockIdx.x;
    const int tileid = (bid & 7) * 32 + (bid >> 3);
    const int bm = tileid >> 5;     // 0..7
    const int bn = tileid & 31;     // 0..31

    // ---- staging geometry: lane -> (subrow = lane>>3, slot = lane&7) ----
    // load l covers rows [l*64 + wave*8, +8); (row & 7) == subrow
    const int subrow = lane >> 3;
    const int slot   = lane & 7;
    const int scol   = (slot ^ subrow) * 8;   // pre-swizzled global col (elems)
    const unsigned short* aBase =
        A + (size_t)(bm * BM + wave * 8 + subrow) * HID + scol;
    const unsigned short* bBase =
        B + (size_t)(bn * BN + wave * 8 + subrow) * HID + scol;
    const int ldsW = wave * 8 * BK;           // wave-uniform LDS elem offset

#define ST_A(buf, ktv, l) __builtin_amdgcn_global_load_lds(                     \
        (gas1_ptr)(aBase + (size_t)(ktv) * BK + (size_t)(l) * 64 * HID),        \
        (las3_ptr)(&lsA[buf][(l) * 64 * BK + ldsW]), 16, 0, 0)
#define ST_B(buf, ktv, l) __builtin_amdgcn_global_load_lds(                     \
        (gas1_ptr)(bBase + (size_t)(ktv) * BK + (size_t)(l) * 64 * HID),        \
        (las3_ptr)(&lsB[buf][(l) * 64 * BK + ldsW]), 16, 0, 0)

    // ---- fragment geometry ----
    const int fr    = lane & 15;
    const int fq    = lane >> 4;
    const int axor  = fr & 7;                  // (row & 7) for fragment rows
    const int koff0 = ((0 + fq) ^ axor) * 8;   // k-slice s=0
    const int koff1 = ((4 + fq) ^ axor) * 8;   // k-slice s=1
    const int aRowB = (wm * 128 + fr) * BK;
    const int bRowB = (wn * 64 + fr) * BK;

#define RD_A(dst, p, mm, koff) dst = __builtin_bit_cast(bf16x8,                 \
        *(const s16x8*)&lsA[p][aRowB + (mm) * 16 * BK + (koff)])
#define RD_B(dst, p, nn, koff) dst = __builtin_bit_cast(bf16x8,                 \
        *(const s16x8*)&lsB[p][bRowB + (nn) * 16 * BK + (koff)])

#define BARRIER() __builtin_amdgcn_s_barrier()
#define LGKM0()   asm volatile("s_waitcnt lgkmcnt(0)" ::: "memory")
#define VMC4()    asm volatile("s_waitcnt vmcnt(4)" ::: "memory")
#define VMC0()    asm volatile("s_waitcnt vmcnt(0)" ::: "memory")
#define PRIO1()   __builtin_amdgcn_s_setprio(1)
#define PRIO0()   __builtin_amdgcn_s_setprio(0)

    f32x4 acc[8][4] = {};
    bf16x8 va[4][2], vb[4][2];

    // ---- prologue: tile0 (A,B) + tile1 (A); keep tile1.A in flight ----
    ST_A(0, 0, 0); ST_A(0, 0, 1); ST_A(0, 0, 2); ST_A(0, 0, 3);
    ST_B(0, 0, 0); ST_B(0, 0, 1); ST_B(0, 0, 2); ST_B(0, 0, 3);
    ST_A(1, 1, 0); ST_A(1, 1, 1); ST_A(1, 1, 2); ST_A(1, 1, 3);
    VMC4();
    BARRIER();

    for (int kt = 0; kt < KSTEPS; ++kt) {
        const int p = kt & 1;
        const int q = p ^ 1;
        const bool s1 = (kt + 1 < KSTEPS);   // stage B(kt+1)
        const bool s2 = (kt + 2 < KSTEPS);   // stage A(kt+2)

        // ---------- phase 1: read A m0-3 + B n0-1 ; stage B(kt+1) rows 0-127 ----------
        RD_A(va[0][0], p, 0, koff0); RD_A(va[0][1], p, 0, koff1);
        RD_A(va[1][0], p, 1, koff0); RD_A(va[1][1], p, 1, koff1);
        RD_A(va[2][0], p, 2, koff0); RD_A(va[2][1], p, 2, koff1);
        RD_A(va[3][0], p, 3, koff0); RD_A(va[3][1], p, 3, koff1);
        RD_B(vb[0][0], p, 0, koff0); RD_B(vb[0][1], p, 0, koff1);
        RD_B(vb[1][0], p, 1, koff0); RD_B(vb[1][1], p, 1, koff1);
        if (s1) { ST_B(q, kt + 1, 0); ST_B(q, kt + 1, 1); }
        BARRIER();
        LGKM0();
        PRIO1();
        #pragma unroll
        for (int s = 0; s < 2; ++s)
            #pragma unroll
            for (int m = 0; m < 4; ++m)
                #pragma unroll
                for (int n = 0; n < 2; ++n)
                    acc[m][n] = __builtin_amdgcn_mfma_f32_16x16x32_bf16(
                        va[m][s], vb[n][s], acc[m][n], 0, 0, 0);
        PRIO0();
        BARRIER();

        // ---------- phase 2: read B n2-3 ; stage B(kt+1) rows 128-255 ----------
        RD_B(vb[2][0], p, 2, koff0); RD_B(vb[2][1], p, 2, koff1);
        RD_B(vb[3][0], p, 3, koff0); RD_B(vb[3][1], p, 3, koff1);
        if (s1) { ST_B(q, kt + 1, 2); ST_B(q, kt + 1, 3); }
        BARRIER();
        LGKM0();
        PRIO1();
        #pragma unroll
        for (int s = 0; s < 2; ++s)
            #pragma unroll
            for (int m = 0; m < 4; ++m)
                #pragma unroll
                for (int n = 0; n < 2; ++n)
                    acc[m][2 + n] = __builtin_amdgcn_mfma_f32_16x16x32_bf16(
                        va[m][s], vb[2 + n][s], acc[m][2 + n], 0, 0, 0);
        PRIO0();
        BARRIER();

        // ---------- phase 3: read A m4-7 (buf reads complete after this) ----------
        RD_A(va[0][0], p, 4, koff0); RD_A(va[0][1], p, 4, koff1);
        RD_A(va[1][0], p, 5, koff0); RD_A(va[1][1], p, 5, koff1);
        RD_A(va[2][0], p, 6, koff0); RD_A(va[2][1], p, 6, koff1);
        RD_A(va[3][0], p, 7, koff0); RD_A(va[3][1], p, 7, koff1);
        BARRIER();
        LGKM0();
        PRIO1();
        #pragma unroll
        for (int s = 0; s < 2; ++s)
            #pragma unroll
            for (int m = 0; m < 4; ++m)
                #pragma unroll
                for (int n = 0; n < 2; ++n)
                    acc[4 + m][n] = __builtin_amdgcn_mfma_f32_16x16x32_bf16(
                        va[m][s], vb[n][s], acc[4 + m][n], 0, 0, 0);
        PRIO0();
        BARRIER();

        // ---------- phase 4: stage A(kt+2) into buf[p] ; q3 ; counted vmcnt ----------
        if (s2) { ST_A(p, kt + 2, 0); ST_A(p, kt + 2, 1);
                  ST_A(p, kt + 2, 2); ST_A(p, kt + 2, 3); }
        BARRIER();
        PRIO1();
        #pragma unroll
        for (int s = 0; s < 2; ++s)
            #pragma unroll
            for (int m = 0; m < 4; ++m)
                #pragma unroll
                for (int n = 0; n < 2; ++n)
                    acc[4 + m][2 + n] = __builtin_amdgcn_mfma_f32_16x16x32_bf16(
                        va[m][s], vb[2 + n][s], acc[4 + m][2 + n], 0, 0, 0);
        PRIO0();
        if (s2) { VMC4(); } else { VMC0(); }
        BARRIER();
    }

    // ---- epilogue: C/D layout col = lane&15, row = (lane>>4)*4 + j ----
    const long crow0 = (long)bm * BM + wm * 128 + fq * 4;
    const long ccol0 = (long)bn * BN + wn * 64 + fr;
    #pragma unroll
    for (int m = 0; m < 8; ++m)
        #pragma unroll
        for (int n = 0; n < 4; ++n)
            #pragma unroll
            for (int j = 0; j < 4; ++j)
                C[(crow0 + m * 16 + j) * OUTD + ccol0 + n * 16] = acc[m][n][j];
}

extern "C" void kernel_launch(void* const* d_in, const int* in_sizes, int n_in,
                              void* d_out, int out_size, void* d_ws, size_t ws_size,
                              hipStream_t stream) {
    const float* hs = (const float*)d_in[0];
    const float* w  = (const float*)d_in[1];
    float* out = (float*)d_out;

    unsigned short* xb = (unsigned short*)d_ws;              // 16 MB  [SEQ][HID] bf16
    unsigned short* wb = xb + (size_t)SEQ * HID;             // 64 MB  [OUTD][HID] bf16

    hipLaunchKernelGGL(reduce_x_kernel, dim3(2048), dim3(256), 0, stream, hs, xb);
    hipLaunchKernelGGL(convert_w_kernel, dim3(4096), dim3(256), 0, stream, w, wb);
    hipLaunchKernelGGL(gemm_bt_kernel, dim3((SEQ / BM) * (OUTD / BN)), dim3(512),
                       0, stream, xb, wb, out);
}

// Round 3
// 235.061 us; speedup vs baseline: 1.0296x; 1.0296x over previous
//
#include <hip/hip_runtime.h>
#include <hip/hip_bf16.h>

// Problem shapes (fixed):
//   hidden_states fp32 [WORLD=8][SEQ=2048][HID=4096]
//   gate_proj     fp32 [OUTD=8192][HID=4096]
//   out           fp32 [SEQ=2048][OUTD=8192]
// out = (sum_w hs[w]) @ W^T   (reduce-scatter sum commutes into the GEMM)

#define HID   4096
#define SEQ   2048
#define WORLD 8
#define OUTD  8192

typedef __bf16 bf16x8 __attribute__((ext_vector_type(8)));
typedef short  s16x8  __attribute__((ext_vector_type(8)));
typedef float  f32x4  __attribute__((ext_vector_type(4)));

typedef const __attribute__((address_space(1))) void* gas1_ptr;
typedef __attribute__((address_space(3))) void*       las3_ptr;

static __device__ __forceinline__ unsigned short f2bf(float f) {
    union { float f; unsigned u; } v; v.f = f;
    unsigned u = v.u;
    u += 0x7fffu + ((u >> 16) & 1u);   // round-to-nearest-even
    return (unsigned short)(u >> 16);
}

// ------------- Kernel 1: fused (reduce over world + cast) | (cast W) -------------
#define RED_BLOCKS  2048
#define CONV_BLOCKS 4096
__global__ void prep_kernel(const float* __restrict__ hs,
                            const float* __restrict__ w,
                            unsigned short* __restrict__ xb,
                            unsigned short* __restrict__ wb) {
    if (blockIdx.x < RED_BLOCKS) {
        const int total4 = SEQ * HID / 4;
        const float4* h4 = (const float4*)hs;
        ushort4* o4 = (ushort4*)xb;
        for (int i = blockIdx.x * blockDim.x + threadIdx.x; i < total4;
             i += RED_BLOCKS * blockDim.x) {
            float4 s = h4[i];
            #pragma unroll
            for (int ww = 1; ww < WORLD; ++ww) {
                float4 t = h4[i + ww * total4];
                s.x += t.x; s.y += t.y; s.z += t.z; s.w += t.w;
            }
            ushort4 o;
            o.x = f2bf(s.x); o.y = f2bf(s.y); o.z = f2bf(s.z); o.w = f2bf(s.w);
            o4[i] = o;
        }
    } else {
        const int total4 = OUTD * HID / 4;
        const float4* w4 = (const float4*)w;
        ushort4* o4 = (ushort4*)wb;
        for (int i = (blockIdx.x - RED_BLOCKS) * blockDim.x + threadIdx.x;
             i < total4; i += CONV_BLOCKS * blockDim.x) {
            float4 s = w4[i];
            ushort4 o;
            o.x = f2bf(s.x); o.y = f2bf(s.y); o.z = f2bf(s.z); o.w = f2bf(s.w);
            o4[i] = o;
        }
    }
}

// ---------------- Kernel 2: 256x256 8-phase bf16 GEMM  C = A * B^T ----------------
// M=SEQ=2048, N=OUTD=8192, K=HID=4096. 8 waves (2Mx4N), 128x64 out per wave.
// LDS: double-buffered A[2][256][64], B[2][256][64] bf16 = 128 KiB, 1 block/CU.
// Swizzle: 16B slot' = slot ^ (row&7); applied on the pre-swizzled GLOBAL source
// (global_load_lds writes linearly) and on the ds_read address (rule #21).
// Phases per K-tile (m-pair x all-n quadrants, 16 MFMA each):
//   ph1: read vb n0-3 (8) + va m0-1 (4)          -> B buffer reads complete here
//   ph2: read va m2-3 (4); stage B(kt+2)->lsB[p]
//   ph3: read va m4-5 + va2 m6-7 (8)             -> A buffer reads complete here
//   ph4: stage A(kt+2)->lsA[p]; MFMA from regs; vmcnt(8)  [never 0 until tail]
// 2D XCD tiling: each XCD owns 4bm x 8bn -> A-tiles shared 8x, B-tiles 4x in L2.

#define BM 256
#define BN 256
#define BK 64
#define KSTEPS (HID / BK)   // 64

__global__ __launch_bounds__(512, 2)
void gemm_bt_kernel(const unsigned short* __restrict__ A,
                    const unsigned short* __restrict__ B,
                    float* __restrict__ C) {
    __shared__ __align__(16) unsigned short lsA[2][BM * BK];   // 64 KiB
    __shared__ __align__(16) unsigned short lsB[2][BN * BK];   // 64 KiB

    const int tid  = threadIdx.x;
    const int lane = tid & 63;
    const int wave = tid >> 6;
    const int wm   = wave >> 2;     // 0..1  -> rows wm*128
    const int wn   = wave & 3;      // 0..3  -> cols wn*64

    // 2D XCD tiling: xcd = bid&7 -> (gm,gn)=(xcd>>2, xcd&3); local 32 blocks = 4x8.
    const int bid   = blockIdx.x;
    const int xcd   = bid & 7;
    const int local = bid >> 3;               // 0..31
    const int bm = (xcd >> 2) * 4 + (local >> 3);   // 0..7
    const int bn = (xcd & 3) * 8 + (local & 7);     // 0..31

    // ---- staging geometry: lane -> (subrow = lane>>3, slot = lane&7) ----
    // load l covers rows [l*64 + wave*8, +8); (row & 7) == subrow
    const int subrow = lane >> 3;
    const int slot   = lane & 7;
    const int scol   = (slot ^ subrow) * 8;   // pre-swizzled global col (elems)
    const unsigned short* aBase =
        A + (size_t)(bm * BM + wave * 8 + subrow) * HID + scol;
    const unsigned short* bBase =
        B + (size_t)(bn * BN + wave * 8 + subrow) * HID + scol;
    const int ldsW = wave * 8 * BK;           // wave-uniform LDS elem offset

#define ST_A(buf, ktv, l) __builtin_amdgcn_global_load_lds(                     \
        (gas1_ptr)(aBase + (size_t)(ktv) * BK + (size_t)(l) * 64 * HID),        \
        (las3_ptr)(&lsA[buf][(l) * 64 * BK + ldsW]), 16, 0, 0)
#define ST_B(buf, ktv, l) __builtin_amdgcn_global_load_lds(                     \
        (gas1_ptr)(bBase + (size_t)(ktv) * BK + (size_t)(l) * 64 * HID),        \
        (las3_ptr)(&lsB[buf][(l) * 64 * BK + ldsW]), 16, 0, 0)

    // ---- fragment geometry ----
    const int fr    = lane & 15;
    const int fq    = lane >> 4;
    const int axor  = fr & 7;                  // (row & 7) for fragment rows
    const int koff0 = ((0 + fq) ^ axor) * 8;   // k-slice s=0
    const int koff1 = ((4 + fq) ^ axor) * 8;   // k-slice s=1
    const int aRowB = (wm * 128 + fr) * BK;
    const int bRowB = (wn * 64 + fr) * BK;

#define RD_A(dst, p, mm, koff) dst = __builtin_bit_cast(bf16x8,                 \
        *(const s16x8*)&lsA[p][aRowB + (mm) * 16 * BK + (koff)])
#define RD_B(dst, p, nn, koff) dst = __builtin_bit_cast(bf16x8,                 \
        *(const s16x8*)&lsB[p][bRowB + (nn) * 16 * BK + (koff)])

#define BARRIER() __builtin_amdgcn_s_barrier()
#define LGKM0()   asm volatile("s_waitcnt lgkmcnt(0)" ::: "memory")
#define VMC8()    asm volatile("s_waitcnt vmcnt(8)" ::: "memory")
#define VMC0()    asm volatile("s_waitcnt vmcnt(0)" ::: "memory")
#define PRIO1()   __builtin_amdgcn_s_setprio(1)
#define PRIO0()   __builtin_amdgcn_s_setprio(0)

    f32x4 acc[8][4] = {};
    bf16x8 va[2][2], va2[2][2], vb[4][2];

    // ---- prologue: stage tiles 0 and 1 fully; tile1 (8 loads) stays in flight ----
    ST_A(0, 0, 0); ST_A(0, 0, 1); ST_A(0, 0, 2); ST_A(0, 0, 3);
    ST_B(0, 0, 0); ST_B(0, 0, 1); ST_B(0, 0, 2); ST_B(0, 0, 3);
    ST_A(1, 1, 0); ST_A(1, 1, 1); ST_A(1, 1, 2); ST_A(1, 1, 3);
    ST_B(1, 1, 0); ST_B(1, 1, 1); ST_B(1, 1, 2); ST_B(1, 1, 3);
    VMC8();
    BARRIER();

    for (int kt = 0; kt < KSTEPS; ++kt) {
        const int p = kt & 1;
        const bool st = (kt + 2 < KSTEPS);

        // ---------- phase 1: vb n0-3 + va m0-1 ; MFMA m0-1 x n0-3 ----------
        RD_B(vb[0][0], p, 0, koff0); RD_B(vb[0][1], p, 0, koff1);
        RD_B(vb[1][0], p, 1, koff0); RD_B(vb[1][1], p, 1, koff1);
        RD_B(vb[2][0], p, 2, koff0); RD_B(vb[2][1], p, 2, koff1);
        RD_B(vb[3][0], p, 3, koff0); RD_B(vb[3][1], p, 3, koff1);
        RD_A(va[0][0], p, 0, koff0); RD_A(va[0][1], p, 0, koff1);
        RD_A(va[1][0], p, 1, koff0); RD_A(va[1][1], p, 1, koff1);
        BARRIER();
        LGKM0();
        PRIO1();
        #pragma unroll
        for (int s = 0; s < 2; ++s)
            #pragma unroll
            for (int m = 0; m < 2; ++m)
                #pragma unroll
                for (int n = 0; n < 4; ++n)
                    acc[m][n] = __builtin_amdgcn_mfma_f32_16x16x32_bf16(
                        va[m][s], vb[n][s], acc[m][n], 0, 0, 0);
        PRIO0();
        BARRIER();

        // ---------- phase 2: va m2-3 ; stage B(kt+2) ; MFMA m2-3 x n0-3 ----------
        RD_A(va[0][0], p, 2, koff0); RD_A(va[0][1], p, 2, koff1);
        RD_A(va[1][0], p, 3, koff0); RD_A(va[1][1], p, 3, koff1);
        if (st) { ST_B(p, kt + 2, 0); ST_B(p, kt + 2, 1);
                  ST_B(p, kt + 2, 2); ST_B(p, kt + 2, 3); }
        BARRIER();
        LGKM0();
        PRIO1();
        #pragma unroll
        for (int s = 0; s < 2; ++s)
            #pragma unroll
            for (int m = 0; m < 2; ++m)
                #pragma unroll
                for (int n = 0; n < 4; ++n)
                    acc[2 + m][n] = __builtin_amdgcn_mfma_f32_16x16x32_bf16(
                        va[m][s], vb[n][s], acc[2 + m][n], 0, 0, 0);
        PRIO0();
        BARRIER();

        // ---------- phase 3: va m4-5 + va2 m6-7 ; MFMA m4-5 x n0-3 ----------
        RD_A(va[0][0],  p, 4, koff0); RD_A(va[0][1],  p, 4, koff1);
        RD_A(va[1][0],  p, 5, koff0); RD_A(va[1][1],  p, 5, koff1);
        RD_A(va2[0][0], p, 6, koff0); RD_A(va2[0][1], p, 6, koff1);
        RD_A(va2[1][0], p, 7, koff0); RD_A(va2[1][1], p, 7, koff1);
        BARRIER();
        LGKM0();
        PRIO1();
        #pragma unroll
        for (int s = 0; s < 2; ++s)
            #pragma unroll
            for (int m = 0; m < 2; ++m)
                #pragma unroll
                for (int n = 0; n < 4; ++n)
                    acc[4 + m][n] = __builtin_amdgcn_mfma_f32_16x16x32_bf16(
                        va[m][s], vb[n][s], acc[4 + m][n], 0, 0, 0);
        PRIO0();
        BARRIER();

        // ---------- phase 4: stage A(kt+2) ; MFMA m6-7 x n0-3 ; counted vmcnt ----------
        if (st) { ST_A(p, kt + 2, 0); ST_A(p, kt + 2, 1);
                  ST_A(p, kt + 2, 2); ST_A(p, kt + 2, 3); }
        BARRIER();
        PRIO1();
        #pragma unroll
        for (int s = 0; s < 2; ++s)
            #pragma unroll
            for (int m = 0; m < 2; ++m)
                #pragma unroll
                for (int n = 0; n < 4; ++n)
                    acc[6 + m][n] = __builtin_amdgcn_mfma_f32_16x16x32_bf16(
                        va2[m][s], vb[n][s], acc[6 + m][n], 0, 0, 0);
        PRIO0();
        if (st) { VMC8(); } else { VMC0(); }
        BARRIER();
    }

    // ---- epilogue: C/D layout col = lane&15, row = (lane>>4)*4 + j ----
    const long crow0 = (long)bm * BM + wm * 128 + fq * 4;
    const long ccol0 = (long)bn * BN + wn * 64 + fr;
    #pragma unroll
    for (int m = 0; m < 8; ++m)
        #pragma unroll
        for (int n = 0; n < 4; ++n)
            #pragma unroll
            for (int j = 0; j < 4; ++j)
                C[(crow0 + m * 16 + j) * OUTD + ccol0 + n * 16] = acc[m][n][j];
}

extern "C" void kernel_launch(void* const* d_in, const int* in_sizes, int n_in,
                              void* d_out, int out_size, void* d_ws, size_t ws_size,
                              hipStream_t stream) {
    const float* hs = (const float*)d_in[0];
    const float* w  = (const float*)d_in[1];
    float* out = (float*)d_out;

    unsigned short* xb = (unsigned short*)d_ws;              // 16 MB  [SEQ][HID] bf16
    unsigned short* wb = xb + (size_t)SEQ * HID;             // 64 MB  [OUTD][HID] bf16

    hipLaunchKernelGGL(prep_kernel, dim3(RED_BLOCKS + CONV_BLOCKS), dim3(256),
                       0, stream, hs, w, xb, wb);
    hipLaunchKernelGGL(gemm_bt_kernel, dim3((SEQ / BM) * (OUTD / BN)), dim3(512),
                       0, stream, xb, wb, out);
}

// Round 4
// 223.030 us; speedup vs baseline: 1.0851x; 1.0539x over previous
//
#include <hip/hip_runtime.h>
#include <hip/hip_bf16.h>

// Problem shapes (fixed):
//   hidden_states fp32 [WORLD=8][SEQ=2048][HID=4096]
//   gate_proj     fp32 [OUTD=8192][HID=4096]
//   out           fp32 [SEQ=2048][OUTD=8192]
// out = (sum_w hs[w]) @ W^T   (reduce-scatter sum commutes into the GEMM)

#define HID   4096
#define SEQ   2048
#define WORLD 8
#define OUTD  8192

typedef __bf16 bf16x8 __attribute__((ext_vector_type(8)));
typedef short  s16x8  __attribute__((ext_vector_type(8)));
typedef float  f32x4  __attribute__((ext_vector_type(4)));

typedef const __attribute__((address_space(1))) void* gas1_ptr;
typedef __attribute__((address_space(3))) void*       las3_ptr;

static __device__ __forceinline__ unsigned short f2bf(float f) {
    union { float f; unsigned u; } v; v.f = f;
    unsigned u = v.u;
    u += 0x7fffu + ((u >> 16) & 1u);   // round-to-nearest-even
    return (unsigned short)(u >> 16);
}

// ------------- Kernel 1: fused (reduce over world + cast) | (cast W) -------------
#define RED_BLOCKS  2048
#define CONV_BLOCKS 4096
__global__ void prep_kernel(const float* __restrict__ hs,
                            const float* __restrict__ w,
                            unsigned short* __restrict__ xb,
                            unsigned short* __restrict__ wb) {
    if (blockIdx.x < RED_BLOCKS) {
        const int total4 = SEQ * HID / 4;
        const float4* h4 = (const float4*)hs;
        ushort4* o4 = (ushort4*)xb;
        for (int i = blockIdx.x * blockDim.x + threadIdx.x; i < total4;
             i += RED_BLOCKS * blockDim.x) {
            float4 s = h4[i];
            #pragma unroll
            for (int ww = 1; ww < WORLD; ++ww) {
                float4 t = h4[i + ww * total4];
                s.x += t.x; s.y += t.y; s.z += t.z; s.w += t.w;
            }
            ushort4 o;
            o.x = f2bf(s.x); o.y = f2bf(s.y); o.z = f2bf(s.z); o.w = f2bf(s.w);
            o4[i] = o;
        }
    } else {
        const int total4 = OUTD * HID / 4;
        const float4* w4 = (const float4*)w;
        ushort4* o4 = (ushort4*)wb;
        for (int i = (blockIdx.x - RED_BLOCKS) * blockDim.x + threadIdx.x;
             i < total4; i += CONV_BLOCKS * blockDim.x) {
            float4 s = w4[i];
            ushort4 o;
            o.x = f2bf(s.x); o.y = f2bf(s.y); o.z = f2bf(s.z); o.w = f2bf(s.w);
            o4[i] = o;
        }
    }
}

// ------------ Kernel 2: 256x256 8-phase (2 K-tiles/iter) bf16 GEMM C = A*B^T ------------
// Faithful m201-template port: compile-time buffer indices (2 K-tiles unrolled),
// 2 global_load_lds per phase (half-tile), vmcnt(6) ONLY at phases 4 and 8
// (3 half-tiles in flight), lgkmcnt(8) hint on 12-read phases, raw s_barrier,
// setprio around MFMA clusters. Swizzle: 16B slot' = slot ^ (row&7), applied on
// the pre-swizzled GLOBAL source + on ds_read (both-sides rule).
// Stage order per iter (tiles t,t+1):
//  ph1:A(t+1)h1 ph2:B(t+2)h0 ph3:B(t+2)h1 ph4:A(t+2)h0 | ph5:A(t+2)h1
//  ph6:B(t+3)h0 ph7:B(t+3)h1 ph8:A(t+3)h0   [next ph1 stages A(t+3)h1]

#define BM 256
#define BN 256
#define BK 64
#define KSTEPS (HID / BK)   // 64

__global__ __launch_bounds__(512, 2)
void gemm_bt_kernel(const unsigned short* __restrict__ A,
                    const unsigned short* __restrict__ B,
                    float* __restrict__ C) {
    __shared__ __align__(16) unsigned short lsA[2][BM * BK];   // 64 KiB
    __shared__ __align__(16) unsigned short lsB[2][BN * BK];   // 64 KiB

    const int tid  = threadIdx.x;
    const int lane = tid & 63;
    const int wave = tid >> 6;
    const int wm   = wave >> 2;     // 0..1  -> rows wm*128
    const int wn   = wave & 3;      // 0..3  -> cols wn*64

    // 2D XCD tiling: xcd = bid&7 -> (gm,gn)=(xcd>>2, xcd&3); local 32 blocks = 4x8.
    const int bid   = blockIdx.x;
    const int xcd   = bid & 7;
    const int local = bid >> 3;               // 0..31
    const int bm = (xcd >> 2) * 4 + (local >> 3);   // 0..7
    const int bn = (xcd & 3) * 8 + (local & 7);     // 0..31

    // ---- staging geometry: lane -> (subrow = lane>>3, slot = lane&7) ----
    // load l (l=0..3) covers rows [l*64 + wave*8, +8); (row & 7) == subrow
    const int subrow = lane >> 3;
    const int slot   = lane & 7;
    const int scol   = (slot ^ subrow) * 8;   // pre-swizzled global col (elems)
    const unsigned short* aBase =
        A + (size_t)(bm * BM + wave * 8 + subrow) * HID + scol;
    const unsigned short* bBase =
        B + (size_t)(bn * BN + wave * 8 + subrow) * HID + scol;
    const int ldsW = wave * 8 * BK;           // wave-uniform LDS elem offset

#define ST_A(buf, ktv, l) __builtin_amdgcn_global_load_lds(                     \
        (gas1_ptr)(aBase + (size_t)(ktv) * BK + (size_t)(l) * 64 * HID),        \
        (las3_ptr)(&lsA[buf][(l) * 64 * BK + ldsW]), 16, 0, 0)
#define ST_B(buf, ktv, l) __builtin_amdgcn_global_load_lds(                     \
        (gas1_ptr)(bBase + (size_t)(ktv) * BK + (size_t)(l) * 64 * HID),        \
        (las3_ptr)(&lsB[buf][(l) * 64 * BK + ldsW]), 16, 0, 0)
// stage one half-tile h (h=0,1) = 2 global_load_lds
#define STG_A(buf, ktv, h) do { ST_A(buf, ktv, 2*(h)); ST_A(buf, ktv, 2*(h)+1); } while (0)
#define STG_B(buf, ktv, h) do { ST_B(buf, ktv, 2*(h)); ST_B(buf, ktv, 2*(h)+1); } while (0)

    // ---- fragment geometry ----
    const int fr    = lane & 15;
    const int fq    = lane >> 4;
    const int axor  = fr & 7;                  // (row & 7) for fragment rows
    const int koff0 = ((0 + fq) ^ axor) * 8;   // k-slice s=0
    const int koff1 = ((4 + fq) ^ axor) * 8;   // k-slice s=1
    const int aRowB = (wm * 128 + fr) * BK;
    const int bRowB = (wn * 64 + fr) * BK;

#define RD_A(dst, P, mm, koff) dst = __builtin_bit_cast(bf16x8,                 \
        *(const s16x8*)&lsA[P][aRowB + (mm) * 16 * BK + (koff)])
#define RD_B(dst, P, nn, koff) dst = __builtin_bit_cast(bf16x8,                 \
        *(const s16x8*)&lsB[P][bRowB + (nn) * 16 * BK + (koff)])

#define BARRIER() __builtin_amdgcn_s_barrier()
#define LGKM0()   asm volatile("s_waitcnt lgkmcnt(0)" ::: "memory")
#define LGKM8()   asm volatile("s_waitcnt lgkmcnt(8)" ::: "memory")
#define VMC6()    asm volatile("s_waitcnt vmcnt(6)" ::: "memory")
#define VMC0()    asm volatile("s_waitcnt vmcnt(0)" ::: "memory")
#define PRIO1()   __builtin_amdgcn_s_setprio(1)
#define PRIO0()   __builtin_amdgcn_s_setprio(0)

// 16-MFMA cluster: m-pair (mb, mb+1) x n0-3, both k-slices, from array VAx
#define MFMA16(VAx, mb)                                                          \
    PRIO1();                                                                     \
    _Pragma("unroll")                                                            \
    for (int s = 0; s < 2; ++s)                                                  \
        _Pragma("unroll")                                                        \
        for (int m = 0; m < 2; ++m)                                              \
            _Pragma("unroll")                                                    \
            for (int n = 0; n < 4; ++n)                                          \
                acc[(mb) + m][n] = __builtin_amdgcn_mfma_f32_16x16x32_bf16(      \
                    VAx[m][s], vb[n][s], acc[(mb) + m][n], 0, 0, 0);             \
    PRIO0()

// 12-read phase head for buffer P: all B frags + A m0-1
#define READS_PH_FIRST(P)                                                        \
    RD_B(vb[0][0], P, 0, koff0); RD_B(vb[0][1], P, 0, koff1);                    \
    RD_B(vb[1][0], P, 1, koff0); RD_B(vb[1][1], P, 1, koff1);                    \
    RD_B(vb[2][0], P, 2, koff0); RD_B(vb[2][1], P, 2, koff1);                    \
    RD_B(vb[3][0], P, 3, koff0); RD_B(vb[3][1], P, 3, koff1);                    \
    RD_A(va[0][0], P, 0, koff0); RD_A(va[0][1], P, 0, koff1);                    \
    RD_A(va[1][0], P, 1, koff0); RD_A(va[1][1], P, 1, koff1)

    f32x4 acc[8][4] = {};
    bf16x8 va[2][2], va2[2][2], vb[4][2];

    // ---- prologue: tile0 full + tile1 {Bh0,Bh1,Ah0}; A1h1 deferred to ph1 ----
    STG_B(0, 0, 0); STG_B(0, 0, 1); STG_A(0, 0, 0); STG_A(0, 0, 1);
    STG_B(1, 1, 0); STG_B(1, 1, 1); STG_A(1, 1, 0);
    VMC6();          // tile0's 8 loads complete; 3 half-tiles stay in flight
    BARRIER();

    #pragma unroll 1
    for (int t = 0; t < KSTEPS; t += 2) {
        const bool st2 = (t + 2 < KSTEPS);
        const bool st3 = (t + 3 < KSTEPS);

        // ================= K-tile t (buf 0) =================
        // ---- ph1: 12 reads ; stage A(t+1)h1 ; MFMA m0-1 ----
        READS_PH_FIRST(0);
        STG_A(1, t + 1, 1);
        LGKM8();
        BARRIER(); LGKM0();
        MFMA16(va, 0);
        BARRIER();

        // ---- ph2: read A m2-3 ; stage B(t+2)h0 ; MFMA m2-3 ----
        RD_A(va[0][0], 0, 2, koff0); RD_A(va[0][1], 0, 2, koff1);
        RD_A(va[1][0], 0, 3, koff0); RD_A(va[1][1], 0, 3, koff1);
        if (st2) STG_B(0, t + 2, 0);
        BARRIER(); LGKM0();
        MFMA16(va, 2);
        BARRIER();

        // ---- ph3: read A m4-7 ; stage B(t+2)h1 ; MFMA m4-5 ----
        RD_A(va[0][0],  0, 4, koff0); RD_A(va[0][1],  0, 4, koff1);
        RD_A(va[1][0],  0, 5, koff0); RD_A(va[1][1],  0, 5, koff1);
        RD_A(va2[0][0], 0, 6, koff0); RD_A(va2[0][1], 0, 6, koff1);
        RD_A(va2[1][0], 0, 7, koff0); RD_A(va2[1][1], 0, 7, koff1);
        if (st2) STG_B(0, t + 2, 1);
        BARRIER(); LGKM0();
        MFMA16(va, 4);
        BARRIER();

        // ---- ph4: stage A(t+2)h0 ; MFMA m6-7 ; vmcnt(6) ----
        if (st2) STG_A(0, t + 2, 0);
        BARRIER();
        MFMA16(va2, 6);
        if (st2) { VMC6(); } else { VMC0(); }
        BARRIER();

        // ================= K-tile t+1 (buf 1) =================
        // ---- ph5: 12 reads ; stage A(t+2)h1 ; MFMA m0-1 ----
        READS_PH_FIRST(1);
        if (st2) STG_A(0, t + 2, 1);
        LGKM8();
        BARRIER(); LGKM0();
        MFMA16(va, 0);
        BARRIER();

        // ---- ph6: read A m2-3 ; stage B(t+3)h0 ; MFMA m2-3 ----
        RD_A(va[0][0], 1, 2, koff0); RD_A(va[0][1], 1, 2, koff1);
        RD_A(va[1][0], 1, 3, koff0); RD_A(va[1][1], 1, 3, koff1);
        if (st3) STG_B(1, t + 3, 0);
        BARRIER(); LGKM0();
        MFMA16(va, 2);
        BARRIER();

        // ---- ph7: read A m4-7 ; stage B(t+3)h1 ; MFMA m4-5 ----
        RD_A(va[0][0],  1, 4, koff0); RD_A(va[0][1],  1, 4, koff1);
        RD_A(va[1][0],  1, 5, koff0); RD_A(va[1][1],  1, 5, koff1);
        RD_A(va2[0][0], 1, 6, koff0); RD_A(va2[0][1], 1, 6, koff1);
        RD_A(va2[1][0], 1, 7, koff0); RD_A(va2[1][1], 1, 7, koff1);
        if (st3) STG_B(1, t + 3, 1);
        BARRIER(); LGKM0();
        MFMA16(va, 4);
        BARRIER();

        // ---- ph8: stage A(t+3)h0 ; MFMA m6-7 ; vmcnt(6) ----
        if (st3) STG_A(1, t + 3, 0);
        BARRIER();
        MFMA16(va2, 6);
        if (st3) { VMC6(); } else { VMC0(); }
        BARRIER();
    }

    // ---- epilogue: C/D layout col = lane&15, row = (lane>>4)*4 + j ----
    const long crow0 = (long)bm * BM + wm * 128 + fq * 4;
    const long ccol0 = (long)bn * BN + wn * 64 + fr;
    #pragma unroll
    for (int m = 0; m < 8; ++m)
        #pragma unroll
        for (int n = 0; n < 4; ++n)
            #pragma unroll
            for (int j = 0; j < 4; ++j)
                C[(crow0 + m * 16 + j) * OUTD + ccol0 + n * 16] = acc[m][n][j];
}

extern "C" void kernel_launch(void* const* d_in, const int* in_sizes, int n_in,
                              void* d_out, int out_size, void* d_ws, size_t ws_size,
                              hipStream_t stream) {
    const float* hs = (const float*)d_in[0];
    const float* w  = (const float*)d_in[1];
    float* out = (float*)d_out;

    unsigned short* xb = (unsigned short*)d_ws;              // 16 MB  [SEQ][HID] bf16
    unsigned short* wb = xb + (size_t)SEQ * HID;             // 64 MB  [OUTD][HID] bf16

    hipLaunchKernelGGL(prep_kernel, dim3(RED_BLOCKS + CONV_BLOCKS), dim3(256),
                       0, stream, hs, w, xb, wb);
    hipLaunchKernelGGL(gemm_bt_kernel, dim3((SEQ / BM) * (OUTD / BN)), dim3(512),
                       0, stream, xb, wb, out);
}